// Round 11
// baseline (186.052 us; speedup 1.0000x reference)
//
#include <hip/hip_runtime.h>
#include <hip/hip_bf16.h>

typedef __bf16 bf16x8 __attribute__((ext_vector_type(8)));
typedef float f32x4 __attribute__((ext_vector_type(4)));
typedef float f32x16 __attribute__((ext_vector_type(16)));
typedef int int4v __attribute__((ext_vector_type(4)));
typedef unsigned int uint4v __attribute__((ext_vector_type(4)));
typedef unsigned short u16x8 __attribute__((ext_vector_type(8)));

#define N_NODES 8192
#define D_FEAT 128

// Round-11: r6 body + ONE change. __syncthreads() emits
// s_waitcnt vmcnt(0) before s_barrier -> it drained the distance-2 A
// prefetch EVERY chunk (MLP ~0, explains 3.8-5.1 TB/s ceilings across all
// probes). Replace in-loop barriers with lgkmcnt(0)-only barrier (LDS
// ordering preserved; global loads stay in flight; compiler's automatic
// counted vmcnt before first register use does the rest). T4 pattern.

// LDS-only barrier: orders bitsL producer/consumer without draining vmcnt.
__device__ __forceinline__ void lds_barrier() {
  __builtin_amdgcn_sched_barrier(0);
  asm volatile("s_waitcnt lgkmcnt(0)" ::: "memory");
  __builtin_amdgcn_s_barrier();
  __builtin_amdgcn_sched_barrier(0);
}

// ---------------------------------------------------------------------------
__device__ __forceinline__ bf16x8 unpack_byte(unsigned dword, int sh) {
  unsigned P = ((dword >> sh) & 0xFFu) * 0x8001u;
  uint4v c;
  c[0] = (P & 0x10001u) * 0x3F80u;
  c[1] = ((P >> 2) & 0x10001u) * 0x3F80u;
  c[2] = ((P >> 4) & 0x10001u) * 0x3F80u;
  c[3] = ((P >> 6) & 0x10001u) * 0x3F80u;
  return __builtin_bit_cast(bf16x8, c);
}

// ---------------------------------------------------------------------------
// Bpk fragment build (verified rounds 2-6). Fragment f = kk*256 + ng*64 + l
// holds, at element e: F[sigma(kk*16 + (l>>5)*8 + e)][ng*32 + (l&31)],
// sigma(p) = 256*(p>>8) + 32*((p>>3)&7) + 4*(p&7) + ((p>>6)&3)
__device__ __forceinline__ void bpk32_store(const float* __restrict__ src,
                                            unsigned short* __restrict__ Bpk,
                                            int W) {
  const int kk = W >> 8;
  const int ng = (W >> 6) & 3;
  const int l = W & 63;
  const int d = ng * 32 + (l & 31);
  const int p0 = kk * 16 + (l >> 5) * 8;
  const int n0 = (p0 >> 8) * 256 + ((p0 >> 3) & 7) * 32 + ((p0 >> 6) & 3);
  u16x8 pk;
#pragma unroll
  for (int e = 0; e < 8; ++e) {
    __bf16 v = (__bf16)src[(long)(n0 + 4 * e) * D_FEAT + d];
    pk[e] = __builtin_bit_cast(unsigned short, v);
  }
  *(u16x8*)(Bpk + (long)W * 8) = pk;
}

__global__ __launch_bounds__(256) void bpk_build32_kernel(
    const float* __restrict__ src, unsigned short* __restrict__ Bpk) {
  bpk32_store(src, Bpk, blockIdx.x * 256 + threadIdx.x);
}

// ---------------------------------------------------------------------------
// Fused pack+GEMM layer (round-6 geometry, verified). Block = 32 rows x
// 128 cols, 512 thr = 8 waves = 4 ng x 2 kh2; 32 chunks of 256 ints.
__global__ __launch_bounds__(512, 2) void fused_layer_kernel(
    const int* __restrict__ adj, const unsigned short* __restrict__ Bpk,
    const float* __restrict__ fin, float* __restrict__ fout) {
  __shared__ unsigned bitsL[2][320];              // [buf][row*10 + slot]
  __shared__ int degL[32];
  __shared__ __align__(16) f32x4 red[4][4][64];   // 16 KiB split-K combine

  const int tid = threadIdx.x;
  const int lane = tid & 63;
  const int w = tid >> 6;       // 0..7
  const int ng = w & 3;         // 32-col group
  const int kh2 = w >> 2;       // K-half of each chunk
  const int l31 = lane & 31;
  const int lh = lane >> 5;
  const int lh8 = lh * 8;
  const int m0 = blockIdx.x * 32;

  const int4v* aB0 = (const int4v*)(adj + ((long)(m0 + w) << 13)) + lane;
  const int4v* aB1 = (const int4v*)(adj + ((long)(m0 + 8 + w) << 13)) + lane;
  const int4v* aB2 = (const int4v*)(adj + ((long)(m0 + 16 + w) << 13)) + lane;
  const int4v* aB3 = (const int4v*)(adj + ((long)(m0 + 24 + w) << 13)) + lane;

  int cnt0 = 0, cnt1 = 0, cnt2 = 0, cnt3 = 0;

#define DO_BALLOT(R0, R1, R2, R3, BUF)                                       \
  {                                                                          \
    const int e_ = lane >> 1;                                                \
    _Pragma("unroll") for (int i = 0; i < 4; ++i) {                          \
      int4v vv = (i == 0) ? (R0) : (i == 1) ? (R1) : (i == 2) ? (R2) : (R3); \
      unsigned long long b0 = __ballot(vv[0] != 0);                          \
      unsigned long long b1 = __ballot(vv[1] != 0);                          \
      unsigned long long b2 = __ballot(vv[2] != 0);                          \
      unsigned long long b3 = __ballot(vv[3] != 0);                          \
      int pc = __popcll(b0) + __popcll(b1) + __popcll(b2) + __popcll(b3);    \
      if (i == 0) cnt0 += pc;                                                \
      if (i == 1) cnt1 += pc;                                                \
      if (i == 2) cnt2 += pc;                                                \
      if (i == 3) cnt3 += pc;                                                \
      unsigned long long bsel = b0;                                          \
      if (e_ == 1) bsel = b1;                                                \
      if (e_ == 2) bsel = b2;                                                \
      if (e_ == 3) bsel = b3;                                                \
      unsigned dv = (lane & 1) ? (unsigned)(bsel >> 32) : (unsigned)bsel;    \
      if (lane < 8) bitsL[BUF][(i * 8 + w) * 10 + lane] = dv;                \
    }                                                                        \
  }

  f32x16 acc = {0.f, 0.f, 0.f, 0.f, 0.f, 0.f, 0.f, 0.f,
                0.f, 0.f, 0.f, 0.f, 0.f, 0.f, 0.f, 0.f};

#define DO_GEMM(C, BUF)                                                      \
  {                                                                          \
    const bf16x8* bp = (const bf16x8*)Bpk +                                  \
                       (((long)((C)*16 + kh2 * 8)) << 8) + ng * 64 + lane;   \
    bf16x8 bv0 = bp[0], bv1 = bp[256], bv2 = bp[512], bv3 = bp[768];         \
    bf16x8 bv4 = bp[1024], bv5 = bp[1280], bv6 = bp[1536], bv7 = bp[1792];   \
    const unsigned* bl = &bitsL[BUF][l31 * 10 + kh2 * 4];                    \
    unsigned q0 = bl[0], q1 = bl[1], q2 = bl[2], q3 = bl[3];                 \
    acc = __builtin_amdgcn_mfma_f32_32x32x16_bf16(unpack_byte(q0, lh8),      \
                                                  bv0, acc, 0, 0, 0);        \
    acc = __builtin_amdgcn_mfma_f32_32x32x16_bf16(unpack_byte(q0, lh8 + 16), \
                                                  bv1, acc, 0, 0, 0);        \
    acc = __builtin_amdgcn_mfma_f32_32x32x16_bf16(unpack_byte(q1, lh8),      \
                                                  bv2, acc, 0, 0, 0);        \
    acc = __builtin_amdgcn_mfma_f32_32x32x16_bf16(unpack_byte(q1, lh8 + 16), \
                                                  bv3, acc, 0, 0, 0);        \
    acc = __builtin_amdgcn_mfma_f32_32x32x16_bf16(unpack_byte(q2, lh8),      \
                                                  bv4, acc, 0, 0, 0);        \
    acc = __builtin_amdgcn_mfma_f32_32x32x16_bf16(unpack_byte(q2, lh8 + 16), \
                                                  bv5, acc, 0, 0, 0);        \
    acc = __builtin_amdgcn_mfma_f32_32x32x16_bf16(unpack_byte(q3, lh8),      \
                                                  bv6, acc, 0, 0, 0);        \
    acc = __builtin_amdgcn_mfma_f32_32x32x16_bf16(unpack_byte(q3, lh8 + 16), \
                                                  bv7, acc, 0, 0, 0);        \
  }

  // Prologue: chunk 0 -> avA, chunk 1 -> avB, ballot chunk 0.
  int4v avA0 = aB0[0], avA1 = aB1[0], avA2 = aB2[0], avA3 = aB3[0];
  int4v avB0 = aB0[64], avB1 = aB1[64], avB2 = aB2[64], avB3 = aB3[64];
  DO_BALLOT(avA0, avA1, avA2, avA3, 0)
  lds_barrier();

  // BODY(c): prefetch chunk c+2 into CUR; ballot chunk c+1 from OTH;
  // GEMM chunk c; LDS-only barrier (global loads stay in flight).
#define BODY(C, CUR0, CUR1, CUR2, CUR3, OTH0, OTH1, OTH2, OTH3)              \
  {                                                                          \
    if ((C) + 2 < 32) {                                                      \
      CUR0 = aB0[((C) + 2) * 64];                                            \
      CUR1 = aB1[((C) + 2) * 64];                                            \
      CUR2 = aB2[((C) + 2) * 64];                                            \
      CUR3 = aB3[((C) + 2) * 64];                                            \
    }                                                                        \
    if ((C) + 1 < 32) DO_BALLOT(OTH0, OTH1, OTH2, OTH3, ((C) + 1) & 1)       \
    DO_GEMM((C), (C)&1)                                                      \
    lds_barrier();                                                           \
  }

  for (int c = 0; c < 32; c += 2) {
    BODY(c, avA0, avA1, avA2, avA3, avB0, avB1, avB2, avB3)
    BODY(c + 1, avB0, avB1, avB2, avB3, avA0, avA1, avA2, avA3)
  }
#undef BODY
#undef DO_GEMM
#undef DO_BALLOT

  if (lane == 0) {
    degL[w] = cnt0;
    degL[8 + w] = cnt1;
    degL[16 + w] = cnt2;
    degL[24 + w] = cnt3;
  }

  // Split-K2 combine: kh2=1 waves store, kh2=0 waves add. (Full
  // __syncthreads here is fine: loop is done, nothing left to prefetch.)
  if (kh2) {
#define ST4(c)                                                               \
  red[ng][c][lane] = __builtin_shufflevector(acc, acc, 4 * (c), 4 * (c) + 1, \
                                             4 * (c) + 2, 4 * (c) + 3);
    ST4(0) ST4(1) ST4(2) ST4(3)
#undef ST4
  }
  __syncthreads();
  if (kh2) return;
#pragma unroll
  for (int c = 0; c < 4; ++c) {
    f32x4 r = red[ng][c][lane];
#pragma unroll
    for (int k = 0; k < 4; ++k) acc[4 * c + k] += r[k];
  }

  // Epilogue (verified m101 C/D layout): col = ng*32+l31,
  // row32 = (r&3) + 8*(r>>2) + 4*lh.
#pragma unroll
  for (int r = 0; r < 16; ++r) {
    const int row32 = (r & 3) + 8 * (r >> 2) + 4 * lh;
    const int row = m0 + row32;
    const int dg = degL[row32];
    const long off = (long)row * D_FEAT + ng * 32 + l31;
    fout[off] = dg > 0 ? acc[r] * (1.0f / (float)dg) : fin[off];
  }
}

// ---------------------------------------------------------------------------
// Fallback path (round-1 verified), used only if ws too small.
__global__ __launch_bounds__(256) void transpose_cast_kernel(
    const float* __restrict__ src, unsigned short* __restrict__ dst) {
  __shared__ float tile[64][129];
  const int t = threadIdx.x;
  const int nbase = blockIdx.x * 64;
#pragma unroll
  for (int i = 0; i < 32; ++i) {
    int idx = t + i * 256;
    int nl = idx >> 7;
    int d = idx & 127;
    tile[nl][d] = src[(long)(nbase + nl) * D_FEAT + d];
  }
  __syncthreads();
#pragma unroll
  for (int i = 0; i < 32; ++i) {
    int idx = t + i * 256;
    int d = idx >> 6;
    int nl = idx & 63;
    __bf16 b = (__bf16)tile[nl][d];
    dst[(long)d * N_NODES + nbase + nl] = __builtin_bit_cast(unsigned short, b);
  }
}

__global__ __launch_bounds__(512) void layer_kernel_direct(
    const int* __restrict__ adj, const unsigned short* __restrict__ BT,
    const float* __restrict__ fin, float* __restrict__ fout) {
  const int tid = threadIdx.x;
  const int lane = tid & 63;
  const int w = tid >> 6;
  const int m0 = blockIdx.x * 32 + (w >> 2) * 16;
  const int n0 = (w & 3) * 32;
  const int lr = lane & 15;
  const int kc = lane >> 4;

  const int4v* ap = (const int4v*)(adj + (long)(m0 + lr) * N_NODES + kc * 8);
  const bf16x8* bp0 = (const bf16x8*)(BT + (long)(n0 + lr) * N_NODES + kc * 8);
  const bf16x8* bp1 =
      (const bf16x8*)(BT + (long)(n0 + 16 + lr) * N_NODES + kc * 8);

  f32x4 acc0 = {0.f, 0.f, 0.f, 0.f};
  f32x4 acc1 = {0.f, 0.f, 0.f, 0.f};
  int degv = 0;

#pragma unroll 4
  for (int k = 0; k < N_NODES; k += 32) {
    int4v alo = ap[0];
    int4v ahi = ap[1];
    bf16x8 b0 = bp0[0];
    bf16x8 b1 = bp1[0];
    ap += 8;
    bp0 += 4;
    bp1 += 4;
    unsigned short u[8];
    u[0] = alo[0] ? 0x3F80 : 0;
    u[1] = alo[1] ? 0x3F80 : 0;
    u[2] = alo[2] ? 0x3F80 : 0;
    u[3] = alo[3] ? 0x3F80 : 0;
    u[4] = ahi[0] ? 0x3F80 : 0;
    u[5] = ahi[1] ? 0x3F80 : 0;
    u[6] = ahi[2] ? 0x3F80 : 0;
    u[7] = ahi[3] ? 0x3F80 : 0;
    degv += alo[0] + alo[1] + alo[2] + alo[3] + ahi[0] + ahi[1] + ahi[2] +
            ahi[3];
    bf16x8 a;
    memcpy(&a, u, 16);
    acc0 = __builtin_amdgcn_mfma_f32_16x16x32_bf16(a, b0, acc0, 0, 0, 0);
    acc1 = __builtin_amdgcn_mfma_f32_16x16x32_bf16(a, b1, acc1, 0, 0, 0);
  }

  degv += __shfl_xor(degv, 16);
  degv += __shfl_xor(degv, 32);
  int dgv[4];
#pragma unroll
  for (int j = 0; j < 4; ++j) dgv[j] = __shfl(degv, kc * 4 + j);

#pragma unroll
  for (int t = 0; t < 2; ++t) {
    const f32x4 acc = t ? acc1 : acc0;
    const int col = n0 + t * 16 + lr;
#pragma unroll
    for (int j = 0; j < 4; ++j) {
      const long off = (long)(m0 + kc * 4 + j) * D_FEAT + col;
      fout[off] = dgv[j] > 0 ? acc[j] * (1.0f / (float)dgv[j]) : fin[off];
    }
  }
}

// ---------------------------------------------------------------------------
extern "C" void kernel_launch(void* const* d_in, const int* in_sizes, int n_in,
                              void* d_out, int out_size, void* d_ws,
                              size_t ws_size, hipStream_t stream) {
  const float* features = (const float*)d_in[0];
  const int* adj = (const int*)d_in[1];
  float* out = (float*)d_out;
  const long NN = (long)N_NODES * N_NODES;

  const size_t BPK_BYTES = (size_t)D_FEAT * N_NODES * 2;  // 2 MiB
  const size_t NEED = BPK_BYTES + 256;

  if (ws_size >= NEED) {
    unsigned short* Bpk = (unsigned short*)d_ws;

    // Layer 1
    bpk_build32_kernel<<<512, 256, 0, stream>>>(features, Bpk);
    fused_layer_kernel<<<256, 512, 0, stream>>>(adj, Bpk, features, out);
    // Layer 2
    bpk_build32_kernel<<<512, 256, 0, stream>>>(out, Bpk);
    fused_layer_kernel<<<256, 512, 0, stream>>>(adj + NN, Bpk, out, out);
  } else {
    // Fallback: round-1 verified path (needs only 2 MiB ws)
    unsigned short* BTw = (unsigned short*)d_ws;
    transpose_cast_kernel<<<N_NODES / 64, 256, 0, stream>>>(features, BTw);
    layer_kernel_direct<<<N_NODES / 32, 512, 0, stream>>>(adj, BTw, features,
                                                          out);
    transpose_cast_kernel<<<N_NODES / 64, 256, 0, stream>>>(out, BTw);
    layer_kernel_direct<<<N_NODES / 32, 512, 0, stream>>>(adj + NN, BTw, out,
                                                          out);
  }
}

// Round 13
// 154.372 us; speedup vs baseline: 1.2052x; 1.2052x over previous
//
#include <hip/hip_runtime.h>
#include <hip/hip_bf16.h>

typedef __bf16 bf16x8 __attribute__((ext_vector_type(8)));
typedef float f32x4 __attribute__((ext_vector_type(4)));
typedef float f32x16 __attribute__((ext_vector_type(16)));
typedef int int4v __attribute__((ext_vector_type(4)));
typedef unsigned int uint4v __attribute__((ext_vector_type(4)));
typedef unsigned short u16x8 __attribute__((ext_vector_type(8)));

#define N_NODES 8192
#define D_FEAT 128

// Round-13: r12 chunk-pair kernel with the crash fixed. r12's LOAD_PAIR
// was an unbraced multi-statement macro under `if` -> D1..D7 loaded
// unconditionally at the loop tail -> OOB read past adj end -> device
// fault. Braced now. Structure: 16 barrier periods of 512 ints/row
// (halves __syncthreads vmcnt-drain events vs r6's 32, doubles bytes in
// flight + compute per period). Ballot / sigma / Bpk / GEMM / C-layout
// formulas byte-identical to verified r6.

// ---------------------------------------------------------------------------
__device__ __forceinline__ bf16x8 unpack_byte(unsigned dword, int sh) {
  unsigned P = ((dword >> sh) & 0xFFu) * 0x8001u;
  uint4v c;
  c[0] = (P & 0x10001u) * 0x3F80u;
  c[1] = ((P >> 2) & 0x10001u) * 0x3F80u;
  c[2] = ((P >> 4) & 0x10001u) * 0x3F80u;
  c[3] = ((P >> 6) & 0x10001u) * 0x3F80u;
  return __builtin_bit_cast(bf16x8, c);
}

// ---------------------------------------------------------------------------
// Bpk fragment build (verified rounds 2-6). Fragment f = kk*256 + ng*64 + l
// holds, at element e: F[sigma(kk*16 + (l>>5)*8 + e)][ng*32 + (l&31)],
// sigma(p) = 256*(p>>8) + 32*((p>>3)&7) + 4*(p&7) + ((p>>6)&3)
__device__ __forceinline__ void bpk32_store(const float* __restrict__ src,
                                            unsigned short* __restrict__ Bpk,
                                            int W) {
  const int kk = W >> 8;
  const int ng = (W >> 6) & 3;
  const int l = W & 63;
  const int d = ng * 32 + (l & 31);
  const int p0 = kk * 16 + (l >> 5) * 8;
  const int n0 = (p0 >> 8) * 256 + ((p0 >> 3) & 7) * 32 + ((p0 >> 6) & 3);
  u16x8 pk;
#pragma unroll
  for (int e = 0; e < 8; ++e) {
    __bf16 v = (__bf16)src[(long)(n0 + 4 * e) * D_FEAT + d];
    pk[e] = __builtin_bit_cast(unsigned short, v);
  }
  *(u16x8*)(Bpk + (long)W * 8) = pk;
}

__global__ __launch_bounds__(256) void bpk_build32_kernel(
    const float* __restrict__ src, unsigned short* __restrict__ Bpk) {
  bpk32_store(src, Bpk, blockIdx.x * 256 + threadIdx.x);
}

// ---------------------------------------------------------------------------
// Fused pack+GEMM layer. Block = 32 rows x 128 cols, 512 thr = 8 waves =
// 4 ng x 2 kh2; 16 pair-iterations, each covering 2 sub-chunks of 256 ints.
__global__ __launch_bounds__(512, 2) void fused_layer_kernel(
    const int* __restrict__ adj, const unsigned short* __restrict__ Bpk,
    const float* __restrict__ fin, float* __restrict__ fout) {
  __shared__ unsigned bitsL[2][2][320];           // [buf][sub][row*10+slot]
  __shared__ int degL[32];
  __shared__ __align__(16) f32x4 red[4][4][64];   // 16 KiB split-K combine

  const int tid = threadIdx.x;
  const int lane = tid & 63;
  const int w = tid >> 6;       // 0..7
  const int ng = w & 3;         // 32-col group
  const int kh2 = w >> 2;       // K-half of each sub-chunk
  const int l31 = lane & 31;
  const int lh = lane >> 5;
  const int lh8 = lh * 8;
  const int m0 = blockIdx.x * 32;

  const int4v* aB0 = (const int4v*)(adj + ((long)(m0 + w) << 13)) + lane;
  const int4v* aB1 = (const int4v*)(adj + ((long)(m0 + 8 + w) << 13)) + lane;
  const int4v* aB2 = (const int4v*)(adj + ((long)(m0 + 16 + w) << 13)) + lane;
  const int4v* aB3 = (const int4v*)(adj + ((long)(m0 + 24 + w) << 13)) + lane;

  int cnt0 = 0, cnt1 = 0, cnt2 = 0, cnt3 = 0;

  // Verified r6 ballot, destination-parametrized.
#define DO_BALLOT_SUB(R0, R1, R2, R3, DST)                                   \
  {                                                                          \
    const int e_ = lane >> 1;                                                \
    _Pragma("unroll") for (int i = 0; i < 4; ++i) {                          \
      int4v vv = (i == 0) ? (R0) : (i == 1) ? (R1) : (i == 2) ? (R2) : (R3); \
      unsigned long long b0 = __ballot(vv[0] != 0);                          \
      unsigned long long b1 = __ballot(vv[1] != 0);                          \
      unsigned long long b2 = __ballot(vv[2] != 0);                          \
      unsigned long long b3 = __ballot(vv[3] != 0);                          \
      int pc = __popcll(b0) + __popcll(b1) + __popcll(b2) + __popcll(b3);    \
      if (i == 0) cnt0 += pc;                                                \
      if (i == 1) cnt1 += pc;                                                \
      if (i == 2) cnt2 += pc;                                                \
      if (i == 3) cnt3 += pc;                                                \
      unsigned long long bsel = b0;                                          \
      if (e_ == 1) bsel = b1;                                                \
      if (e_ == 2) bsel = b2;                                                \
      if (e_ == 3) bsel = b3;                                                \
      unsigned dv = (lane & 1) ? (unsigned)(bsel >> 32) : (unsigned)bsel;    \
      if (lane < 8) (DST)[(i * 8 + w) * 10 + lane] = dv;                     \
    }                                                                        \
  }

  f32x16 acc = {0.f, 0.f, 0.f, 0.f, 0.f, 0.f, 0.f, 0.f,
                0.f, 0.f, 0.f, 0.f, 0.f, 0.f, 0.f, 0.f};

  // Verified r6 GEMM, source-parametrized; CP = physical 256-int chunk.
#define DO_GEMM(CP, SRC)                                                     \
  {                                                                          \
    const bf16x8* bp = (const bf16x8*)Bpk +                                  \
                       (((long)((CP)*16 + kh2 * 8)) << 8) + ng * 64 + lane;  \
    bf16x8 bv0 = bp[0], bv1 = bp[256], bv2 = bp[512], bv3 = bp[768];         \
    bf16x8 bv4 = bp[1024], bv5 = bp[1280], bv6 = bp[1536], bv7 = bp[1792];   \
    const unsigned* bl = &(SRC)[l31 * 10 + kh2 * 4];                         \
    unsigned q0 = bl[0], q1 = bl[1], q2 = bl[2], q3 = bl[3];                 \
    acc = __builtin_amdgcn_mfma_f32_32x32x16_bf16(unpack_byte(q0, lh8),      \
                                                  bv0, acc, 0, 0, 0);        \
    acc = __builtin_amdgcn_mfma_f32_32x32x16_bf16(unpack_byte(q0, lh8 + 16), \
                                                  bv1, acc, 0, 0, 0);        \
    acc = __builtin_amdgcn_mfma_f32_32x32x16_bf16(unpack_byte(q1, lh8),      \
                                                  bv2, acc, 0, 0, 0);        \
    acc = __builtin_amdgcn_mfma_f32_32x32x16_bf16(unpack_byte(q1, lh8 + 16), \
                                                  bv3, acc, 0, 0, 0);        \
    acc = __builtin_amdgcn_mfma_f32_32x32x16_bf16(unpack_byte(q2, lh8),      \
                                                  bv4, acc, 0, 0, 0);        \
    acc = __builtin_amdgcn_mfma_f32_32x32x16_bf16(unpack_byte(q2, lh8 + 16), \
                                                  bv5, acc, 0, 0, 0);        \
    acc = __builtin_amdgcn_mfma_f32_32x32x16_bf16(unpack_byte(q3, lh8),      \
                                                  bv6, acc, 0, 0, 0);        \
    acc = __builtin_amdgcn_mfma_f32_32x32x16_bf16(unpack_byte(q3, lh8 + 16), \
                                                  bv7, acc, 0, 0, 0);        \
  }

  // Pair load: sub0 (chunk 2P) -> D0..D3 (rows 0..3), sub1 -> D4..D7.
  // BRACED: must be a single statement under `if` (r12 crash root cause).
#define LOAD_PAIR(P, D0, D1, D2, D3, D4, D5, D6, D7)                         \
  {                                                                          \
    D0 = aB0[(2 * (P)) * 64];                                                \
    D1 = aB1[(2 * (P)) * 64];                                                \
    D2 = aB2[(2 * (P)) * 64];                                                \
    D3 = aB3[(2 * (P)) * 64];                                                \
    D4 = aB0[(2 * (P) + 1) * 64];                                            \
    D5 = aB1[(2 * (P) + 1) * 64];                                            \
    D6 = aB2[(2 * (P) + 1) * 64];                                            \
    D7 = aB3[(2 * (P) + 1) * 64];                                            \
  }

  int4v pA0, pA1, pA2, pA3, pA4, pA5, pA6, pA7;
  int4v pB0, pB1, pB2, pB3, pB4, pB5, pB6, pB7;

  // Prologue: pair 0 -> pA, pair 1 -> pB; ballot pair 0 into lbuf 0.
  LOAD_PAIR(0, pA0, pA1, pA2, pA3, pA4, pA5, pA6, pA7)
  LOAD_PAIR(1, pB0, pB1, pB2, pB3, pB4, pB5, pB6, pB7)
  DO_BALLOT_SUB(pA0, pA1, pA2, pA3, &bitsL[0][0][0])
  DO_BALLOT_SUB(pA4, pA5, pA6, pA7, &bitsL[0][1][0])
  __syncthreads();

  // BODY(P): prefetch pair P+2 into CUR (regs of pair P, already balloted);
  // ballot pair P+1 from OTH into lbuf (P+1)&1; GEMM pair P from lbuf P&1.
#define BODY(P, C0, C1, C2, C3, C4, C5, C6, C7, O0, O1, O2, O3, O4, O5, O6,  \
             O7)                                                             \
  {                                                                          \
    if ((P) + 2 < 16) LOAD_PAIR((P) + 2, C0, C1, C2, C3, C4, C5, C6, C7)     \
    if ((P) + 1 < 16) {                                                      \
      DO_BALLOT_SUB(O0, O1, O2, O3, &bitsL[((P) + 1) & 1][0][0])             \
      DO_BALLOT_SUB(O4, O5, O6, O7, &bitsL[((P) + 1) & 1][1][0])             \
    }                                                                        \
    DO_GEMM(2 * (P), &bitsL[(P)&1][0][0])                                    \
    DO_GEMM(2 * (P) + 1, &bitsL[(P)&1][1][0])                                \
    __syncthreads();                                                         \
  }

  for (int p = 0; p < 16; p += 2) {
    BODY(p, pA0, pA1, pA2, pA3, pA4, pA5, pA6, pA7, pB0, pB1, pB2, pB3, pB4,
         pB5, pB6, pB7)
    BODY(p + 1, pB0, pB1, pB2, pB3, pB4, pB5, pB6, pB7, pA0, pA1, pA2, pA3,
         pA4, pA5, pA6, pA7)
  }
#undef BODY
#undef LOAD_PAIR
#undef DO_GEMM
#undef DO_BALLOT_SUB

  if (lane == 0) {
    degL[w] = cnt0;
    degL[8 + w] = cnt1;
    degL[16 + w] = cnt2;
    degL[24 + w] = cnt3;
  }

  // Split-K2 combine: kh2=1 waves store, kh2=0 waves add.
  if (kh2) {
#define ST4(c)                                                               \
  red[ng][c][lane] = __builtin_shufflevector(acc, acc, 4 * (c), 4 * (c) + 1, \
                                             4 * (c) + 2, 4 * (c) + 3);
    ST4(0) ST4(1) ST4(2) ST4(3)
#undef ST4
  }
  __syncthreads();
  if (kh2) return;
#pragma unroll
  for (int c = 0; c < 4; ++c) {
    f32x4 r = red[ng][c][lane];
#pragma unroll
    for (int k = 0; k < 4; ++k) acc[4 * c + k] += r[k];
  }

  // Epilogue (verified m101 C/D layout): col = ng*32+l31,
  // row32 = (r&3) + 8*(r>>2) + 4*lh.
#pragma unroll
  for (int r = 0; r < 16; ++r) {
    const int row32 = (r & 3) + 8 * (r >> 2) + 4 * lh;
    const int row = m0 + row32;
    const int dg = degL[row32];
    const long off = (long)row * D_FEAT + ng * 32 + l31;
    fout[off] = dg > 0 ? acc[r] * (1.0f / (float)dg) : fin[off];
  }
}

// ---------------------------------------------------------------------------
// Fallback path (round-1 verified), used only if ws too small.
__global__ __launch_bounds__(256) void transpose_cast_kernel(
    const float* __restrict__ src, unsigned short* __restrict__ dst) {
  __shared__ float tile[64][129];
  const int t = threadIdx.x;
  const int nbase = blockIdx.x * 64;
#pragma unroll
  for (int i = 0; i < 32; ++i) {
    int idx = t + i * 256;
    int nl = idx >> 7;
    int d = idx & 127;
    tile[nl][d] = src[(long)(nbase + nl) * D_FEAT + d];
  }
  __syncthreads();
#pragma unroll
  for (int i = 0; i < 32; ++i) {
    int idx = t + i * 256;
    int d = idx >> 6;
    int nl = idx & 63;
    __bf16 b = (__bf16)tile[nl][d];
    dst[(long)d * N_NODES + nbase + nl] = __builtin_bit_cast(unsigned short, b);
  }
}

__global__ __launch_bounds__(512) void layer_kernel_direct(
    const int* __restrict__ adj, const unsigned short* __restrict__ BT,
    const float* __restrict__ fin, float* __restrict__ fout) {
  const int tid = threadIdx.x;
  const int lane = tid & 63;
  const int w = tid >> 6;
  const int m0 = blockIdx.x * 32 + (w >> 2) * 16;
  const int n0 = (w & 3) * 32;
  const int lr = lane & 15;
  const int kc = lane >> 4;

  const int4v* ap = (const int4v*)(adj + (long)(m0 + lr) * N_NODES + kc * 8);
  const bf16x8* bp0 = (const bf16x8*)(BT + (long)(n0 + lr) * N_NODES + kc * 8);
  const bf16x8* bp1 =
      (const bf16x8*)(BT + (long)(n0 + 16 + lr) * N_NODES + kc * 8);

  f32x4 acc0 = {0.f, 0.f, 0.f, 0.f};
  f32x4 acc1 = {0.f, 0.f, 0.f, 0.f};
  int degv = 0;

#pragma unroll 4
  for (int k = 0; k < N_NODES; k += 32) {
    int4v alo = ap[0];
    int4v ahi = ap[1];
    bf16x8 b0 = bp0[0];
    bf16x8 b1 = bp1[0];
    ap += 8;
    bp0 += 4;
    bp1 += 4;
    unsigned short u[8];
    u[0] = alo[0] ? 0x3F80 : 0;
    u[1] = alo[1] ? 0x3F80 : 0;
    u[2] = alo[2] ? 0x3F80 : 0;
    u[3] = alo[3] ? 0x3F80 : 0;
    u[4] = ahi[0] ? 0x3F80 : 0;
    u[5] = ahi[1] ? 0x3F80 : 0;
    u[6] = ahi[2] ? 0x3F80 : 0;
    u[7] = ahi[3] ? 0x3F80 : 0;
    degv += alo[0] + alo[1] + alo[2] + alo[3] + ahi[0] + ahi[1] + ahi[2] +
            ahi[3];
    bf16x8 a;
    memcpy(&a, u, 16);
    acc0 = __builtin_amdgcn_mfma_f32_16x16x32_bf16(a, b0, acc0, 0, 0, 0);
    acc1 = __builtin_amdgcn_mfma_f32_16x16x32_bf16(a, b1, acc1, 0, 0, 0);
  }

  degv += __shfl_xor(degv, 16);
  degv += __shfl_xor(degv, 32);
  int dgv[4];
#pragma unroll
  for (int j = 0; j < 4; ++j) dgv[j] = __shfl(degv, kc * 4 + j);

#pragma unroll
  for (int t = 0; t < 2; ++t) {
    const f32x4 acc = t ? acc1 : acc0;
    const int col = n0 + t * 16 + lr;
#pragma unroll
    for (int j = 0; j < 4; ++j) {
      const long off = (long)(m0 + kc * 4 + j) * D_FEAT + col;
      fout[off] = dgv[j] > 0 ? acc[j] * (1.0f / (float)dgv[j]) : fin[off];
    }
  }
}

// ---------------------------------------------------------------------------
extern "C" void kernel_launch(void* const* d_in, const int* in_sizes, int n_in,
                              void* d_out, int out_size, void* d_ws,
                              size_t ws_size, hipStream_t stream) {
  const float* features = (const float*)d_in[0];
  const int* adj = (const int*)d_in[1];
  float* out = (float*)d_out;
  const long NN = (long)N_NODES * N_NODES;

  const size_t BPK_BYTES = (size_t)D_FEAT * N_NODES * 2;  // 2 MiB
  const size_t NEED = BPK_BYTES + 256;

  if (ws_size >= NEED) {
    unsigned short* Bpk = (unsigned short*)d_ws;

    // Layer 1
    bpk_build32_kernel<<<512, 256, 0, stream>>>(features, Bpk);
    fused_layer_kernel<<<256, 512, 0, stream>>>(adj, Bpk, features, out);
    // Layer 2
    bpk_build32_kernel<<<512, 256, 0, stream>>>(out, Bpk);
    fused_layer_kernel<<<256, 512, 0, stream>>>(adj + NN, Bpk, out, out);
  } else {
    // Fallback: round-1 verified path (needs only 2 MiB ws)
    unsigned short* BTw = (unsigned short*)d_ws;
    transpose_cast_kernel<<<N_NODES / 64, 256, 0, stream>>>(features, BTw);
    layer_kernel_direct<<<N_NODES / 32, 512, 0, stream>>>(adj, BTw, features,
                                                          out);
    transpose_cast_kernel<<<N_NODES / 64, 256, 0, stream>>>(out, BTw);
    layer_kernel_direct<<<N_NODES / 32, 512, 0, stream>>>(adj + NN, BTw, out,
                                                          out);
  }
}

// Round 14
// 149.402 us; speedup vs baseline: 1.2453x; 1.0333x over previous
//
#include <hip/hip_runtime.h>
#include <hip/hip_bf16.h>

typedef __bf16 bf16x8 __attribute__((ext_vector_type(8)));
typedef float f32x4 __attribute__((ext_vector_type(4)));
typedef float f32x16 __attribute__((ext_vector_type(16)));
typedef int int4v __attribute__((ext_vector_type(4)));
typedef unsigned int uint4v __attribute__((ext_vector_type(4)));
typedef unsigned short u16x8 __attribute__((ext_vector_type(8)));

#define N_NODES 8192
#define D_FEAT 128

// Round-14: two-phase fused layer with SEQUENTIAL panel read.
// Theory: all prior kernels read 32 row-streams/block (8192 machine-wide,
// 1KiB bursts) -> DRAM page thrash caps ~5 TB/s. Phase 1 reads the block's
// 1 MiB panel linearly (256 machine-wide streams, fill-kernel topology),
// ballots into a full-panel LDS bit array (32x the verified r6 per-chunk
// layout; row=i>>2, chunk=(i&3)*8+w, lane ints 4l..4l+3 == r6 mapping).
// Phase 2: verified r6 GEMM over all 32 chunks from LDS, B ping-pong
// prefetched from L2-resident Bpk. sigma/Bpk/C-layout byte-identical r6.

// ---------------------------------------------------------------------------
__device__ __forceinline__ bf16x8 unpack_byte(unsigned dword, int sh) {
  unsigned P = ((dword >> sh) & 0xFFu) * 0x8001u;
  uint4v c;
  c[0] = (P & 0x10001u) * 0x3F80u;
  c[1] = ((P >> 2) & 0x10001u) * 0x3F80u;
  c[2] = ((P >> 4) & 0x10001u) * 0x3F80u;
  c[3] = ((P >> 6) & 0x10001u) * 0x3F80u;
  return __builtin_bit_cast(bf16x8, c);
}

// ---------------------------------------------------------------------------
// Bpk fragment build (verified rounds 2-6). Fragment f = kk*256 + ng*64 + l
// holds, at element e: F[sigma(kk*16 + (l>>5)*8 + e)][ng*32 + (l&31)],
// sigma(p) = 256*(p>>8) + 32*((p>>3)&7) + 4*(p&7) + ((p>>6)&3)
__device__ __forceinline__ void bpk32_store(const float* __restrict__ src,
                                            unsigned short* __restrict__ Bpk,
                                            int W) {
  const int kk = W >> 8;
  const int ng = (W >> 6) & 3;
  const int l = W & 63;
  const int d = ng * 32 + (l & 31);
  const int p0 = kk * 16 + (l >> 5) * 8;
  const int n0 = (p0 >> 8) * 256 + ((p0 >> 3) & 7) * 32 + ((p0 >> 6) & 3);
  u16x8 pk;
#pragma unroll
  for (int e = 0; e < 8; ++e) {
    __bf16 v = (__bf16)src[(long)(n0 + 4 * e) * D_FEAT + d];
    pk[e] = __builtin_bit_cast(unsigned short, v);
  }
  *(u16x8*)(Bpk + (long)W * 8) = pk;
}

__global__ __launch_bounds__(256) void bpk_build32_kernel(
    const float* __restrict__ src, unsigned short* __restrict__ Bpk) {
  bpk32_store(src, Bpk, blockIdx.x * 256 + threadIdx.x);
}

// ---------------------------------------------------------------------------
// Two-phase fused layer. Block = rows [32bx, +32), grid 256, 512 thr.
__global__ __launch_bounds__(512, 2) void fused_layer_kernel(
    const int* __restrict__ adj, const unsigned short* __restrict__ Bpk,
    const float* __restrict__ fin, float* __restrict__ fout) {
  __shared__ unsigned bitsF[32][320];             // 40 KiB [chunk][row*10+slot]
  __shared__ int degL[32];
  __shared__ __align__(16) f32x4 red[4][4][64];   // 16 KiB split-K combine

  const int tid = threadIdx.x;
  const int lane = tid & 63;
  const int w = tid >> 6;       // 0..7
  const int ng = w & 3;         // 32-col group (phase 2)
  const int kh2 = w >> 2;       // K-half of each chunk (phase 2)
  const int l31 = lane & 31;
  const int lh = lane >> 5;
  const int lh8 = lh * 8;
  const int m0 = blockIdx.x * 32;
  const int e_ = lane >> 1;     // ballot slot select (r6 semantics)

  if (tid < 32) degL[tid] = 0;
  __syncthreads();

  // ===== Phase 1: sequential panel read + ballot-pack =====
  // Iteration i: threads cover ints [panel + i*2048, +2048) = quarter
  // (i&3) of row (i>>2). Wave w holds chunk c=(i&3)*8+w; lane l ints
  // [c*256+4l, +4) -- identical per-wave layout to verified r6 ballot.
  const int4v* ap = (const int4v*)(adj + ((long)m0 << 13)) + tid;

#define BALLOT_ONE(V, I, PC)                                                 \
  {                                                                          \
    unsigned long long b0 = __ballot((V)[0] != 0);                           \
    unsigned long long b1 = __ballot((V)[1] != 0);                           \
    unsigned long long b2 = __ballot((V)[2] != 0);                           \
    unsigned long long b3 = __ballot((V)[3] != 0);                           \
    PC += __popcll(b0) + __popcll(b1) + __popcll(b2) + __popcll(b3);         \
    unsigned long long bsel = b0;                                            \
    if (e_ == 1) bsel = b1;                                                  \
    if (e_ == 2) bsel = b2;                                                  \
    if (e_ == 3) bsel = b3;                                                  \
    unsigned dv = (lane & 1) ? (unsigned)(bsel >> 32) : (unsigned)bsel;      \
    if (lane < 8)                                                            \
      bitsF[((((I)) & 3) << 3) + w][(((I)) >> 2) * 10 + lane] = dv;          \
  }

  {
    int4v va = ap[0];
    int4v vb = ap[512];
    int4v vc = ap[1024];
    int4v vd = ap[1536];
    for (int i = 0; i < 128; i += 4) {
      int pc = 0;
      BALLOT_ONE(va, i, pc)
      if (i + 4 < 128) va = ap[(i + 4) * 512];
      BALLOT_ONE(vb, i + 1, pc)
      if (i + 5 < 128) vb = ap[(i + 5) * 512];
      BALLOT_ONE(vc, i + 2, pc)
      if (i + 6 < 128) vc = ap[(i + 6) * 512];
      BALLOT_ONE(vd, i + 3, pc)
      if (i + 7 < 128) vd = ap[(i + 7) * 512];
      if (lane == 0) atomicAdd(&degL[i >> 2], pc);  // all 4 iters same row
    }
  }
#undef BALLOT_ONE
  __syncthreads();

  // ===== Phase 2: GEMM all 32 chunks from LDS bits =====
  f32x16 acc = {0.f, 0.f, 0.f, 0.f, 0.f, 0.f, 0.f, 0.f,
                0.f, 0.f, 0.f, 0.f, 0.f, 0.f, 0.f, 0.f};

  // B fragment j of chunk c at bpb[c*4096 + j*256] (kk = c*16+kh2*8+j, r6).
  const bf16x8* bpb =
      (const bf16x8*)Bpk + ((kh2 * 8) << 8) + ng * 64 + lane;

#define LOADB(BUF, C)                                                        \
  {                                                                          \
    _Pragma("unroll") for (int j = 0; j < 8; ++j)                            \
        BUF[j] = bpb[(long)(C)*4096 + j * 256];                              \
  }

#define COMPUTE(C, BUF)                                                      \
  {                                                                          \
    const unsigned* bl = &bitsF[(C)][l31 * 10 + kh2 * 4];                    \
    unsigned q0 = bl[0], q1 = bl[1], q2 = bl[2], q3 = bl[3];                 \
    acc = __builtin_amdgcn_mfma_f32_32x32x16_bf16(unpack_byte(q0, lh8),      \
                                                  BUF[0], acc, 0, 0, 0);     \
    acc = __builtin_amdgcn_mfma_f32_32x32x16_bf16(unpack_byte(q0, lh8 + 16), \
                                                  BUF[1], acc, 0, 0, 0);     \
    acc = __builtin_amdgcn_mfma_f32_32x32x16_bf16(unpack_byte(q1, lh8),      \
                                                  BUF[2], acc, 0, 0, 0);     \
    acc = __builtin_amdgcn_mfma_f32_32x32x16_bf16(unpack_byte(q1, lh8 + 16), \
                                                  BUF[3], acc, 0, 0, 0);     \
    acc = __builtin_amdgcn_mfma_f32_32x32x16_bf16(unpack_byte(q2, lh8),      \
                                                  BUF[4], acc, 0, 0, 0);     \
    acc = __builtin_amdgcn_mfma_f32_32x32x16_bf16(unpack_byte(q2, lh8 + 16), \
                                                  BUF[5], acc, 0, 0, 0);     \
    acc = __builtin_amdgcn_mfma_f32_32x32x16_bf16(unpack_byte(q3, lh8),      \
                                                  BUF[6], acc, 0, 0, 0);     \
    acc = __builtin_amdgcn_mfma_f32_32x32x16_bf16(unpack_byte(q3, lh8 + 16), \
                                                  BUF[7], acc, 0, 0, 0);     \
  }

  {
    bf16x8 bA[8], bB[8];
    LOADB(bA, 0)
    for (int c = 0; c < 32; c += 2) {
      LOADB(bB, c + 1)
      COMPUTE(c, bA)
      if (c + 2 < 32) LOADB(bA, c + 2)
      COMPUTE(c + 1, bB)
    }
  }
#undef COMPUTE
#undef LOADB

  // Split-K2 combine: kh2=1 waves store, kh2=0 waves add (r6 verified).
  if (kh2) {
#define ST4(c)                                                               \
  red[ng][c][lane] = __builtin_shufflevector(acc, acc, 4 * (c), 4 * (c) + 1, \
                                             4 * (c) + 2, 4 * (c) + 3);
    ST4(0) ST4(1) ST4(2) ST4(3)
#undef ST4
  }
  __syncthreads();
  if (kh2) return;
#pragma unroll
  for (int c = 0; c < 4; ++c) {
    f32x4 r = red[ng][c][lane];
#pragma unroll
    for (int k = 0; k < 4; ++k) acc[4 * c + k] += r[k];
  }

  // Epilogue (verified m101 C/D layout): col = ng*32+l31,
  // row32 = (r&3) + 8*(r>>2) + 4*lh.
#pragma unroll
  for (int r = 0; r < 16; ++r) {
    const int row32 = (r & 3) + 8 * (r >> 2) + 4 * lh;
    const int row = m0 + row32;
    const int dg = degL[row32];
    const long off = (long)row * D_FEAT + ng * 32 + l31;
    fout[off] = dg > 0 ? acc[r] * (1.0f / (float)dg) : fin[off];
  }
}

// ---------------------------------------------------------------------------
// Fallback path (round-1 verified), used only if ws too small.
__global__ __launch_bounds__(256) void transpose_cast_kernel(
    const float* __restrict__ src, unsigned short* __restrict__ dst) {
  __shared__ float tile[64][129];
  const int t = threadIdx.x;
  const int nbase = blockIdx.x * 64;
#pragma unroll
  for (int i = 0; i < 32; ++i) {
    int idx = t + i * 256;
    int nl = idx >> 7;
    int d = idx & 127;
    tile[nl][d] = src[(long)(nbase + nl) * D_FEAT + d];
  }
  __syncthreads();
#pragma unroll
  for (int i = 0; i < 32; ++i) {
    int idx = t + i * 256;
    int d = idx >> 6;
    int nl = idx & 63;
    __bf16 b = (__bf16)tile[nl][d];
    dst[(long)d * N_NODES + nbase + nl] = __builtin_bit_cast(unsigned short, b);
  }
}

__global__ __launch_bounds__(512) void layer_kernel_direct(
    const int* __restrict__ adj, const unsigned short* __restrict__ BT,
    const float* __restrict__ fin, float* __restrict__ fout) {
  const int tid = threadIdx.x;
  const int lane = tid & 63;
  const int w = tid >> 6;
  const int m0 = blockIdx.x * 32 + (w >> 2) * 16;
  const int n0 = (w & 3) * 32;
  const int lr = lane & 15;
  const int kc = lane >> 4;

  const int4v* ap = (const int4v*)(adj + (long)(m0 + lr) * N_NODES + kc * 8);
  const bf16x8* bp0 = (const bf16x8*)(BT + (long)(n0 + lr) * N_NODES + kc * 8);
  const bf16x8* bp1 =
      (const bf16x8*)(BT + (long)(n0 + 16 + lr) * N_NODES + kc * 8);

  f32x4 acc0 = {0.f, 0.f, 0.f, 0.f};
  f32x4 acc1 = {0.f, 0.f, 0.f, 0.f};
  int degv = 0;

#pragma unroll 4
  for (int k = 0; k < N_NODES; k += 32) {
    int4v alo = ap[0];
    int4v ahi = ap[1];
    bf16x8 b0 = bp0[0];
    bf16x8 b1 = bp1[0];
    ap += 8;
    bp0 += 4;
    bp1 += 4;
    unsigned short u[8];
    u[0] = alo[0] ? 0x3F80 : 0;
    u[1] = alo[1] ? 0x3F80 : 0;
    u[2] = alo[2] ? 0x3F80 : 0;
    u[3] = alo[3] ? 0x3F80 : 0;
    u[4] = ahi[0] ? 0x3F80 : 0;
    u[5] = ahi[1] ? 0x3F80 : 0;
    u[6] = ahi[2] ? 0x3F80 : 0;
    u[7] = ahi[3] ? 0x3F80 : 0;
    degv += alo[0] + alo[1] + alo[2] + alo[3] + ahi[0] + ahi[1] + ahi[2] +
            ahi[3];
    bf16x8 a;
    memcpy(&a, u, 16);
    acc0 = __builtin_amdgcn_mfma_f32_16x16x32_bf16(a, b0, acc0, 0, 0, 0);
    acc1 = __builtin_amdgcn_mfma_f32_16x16x32_bf16(a, b1, acc1, 0, 0, 0);
  }

  degv += __shfl_xor(degv, 16);
  degv += __shfl_xor(degv, 32);
  int dgv[4];
#pragma unroll
  for (int j = 0; j < 4; ++j) dgv[j] = __shfl(degv, kc * 4 + j);

#pragma unroll
  for (int t = 0; t < 2; ++t) {
    const f32x4 acc = t ? acc1 : acc0;
    const int col = n0 + t * 16 + lr;
#pragma unroll
    for (int j = 0; j < 4; ++j) {
      const long off = (long)(m0 + kc * 4 + j) * D_FEAT + col;
      fout[off] = dgv[j] > 0 ? acc[j] * (1.0f / (float)dgv[j]) : fin[off];
    }
  }
}

// ---------------------------------------------------------------------------
extern "C" void kernel_launch(void* const* d_in, const int* in_sizes, int n_in,
                              void* d_out, int out_size, void* d_ws,
                              size_t ws_size, hipStream_t stream) {
  const float* features = (const float*)d_in[0];
  const int* adj = (const int*)d_in[1];
  float* out = (float*)d_out;
  const long NN = (long)N_NODES * N_NODES;

  const size_t BPK_BYTES = (size_t)D_FEAT * N_NODES * 2;  // 2 MiB
  const size_t NEED = BPK_BYTES + 256;

  if (ws_size >= NEED) {
    unsigned short* Bpk = (unsigned short*)d_ws;

    // Layer 1
    bpk_build32_kernel<<<512, 256, 0, stream>>>(features, Bpk);
    fused_layer_kernel<<<256, 512, 0, stream>>>(adj, Bpk, features, out);
    // Layer 2
    bpk_build32_kernel<<<512, 256, 0, stream>>>(out, Bpk);
    fused_layer_kernel<<<256, 512, 0, stream>>>(adj + NN, Bpk, out, out);
  } else {
    // Fallback: round-1 verified path (needs only 2 MiB ws)
    unsigned short* BTw = (unsigned short*)d_ws;
    transpose_cast_kernel<<<N_NODES / 64, 256, 0, stream>>>(features, BTw);
    layer_kernel_direct<<<N_NODES / 32, 512, 0, stream>>>(adj, BTw, features,
                                                          out);
    transpose_cast_kernel<<<N_NODES / 64, 256, 0, stream>>>(out, BTw);
    layer_kernel_direct<<<N_NODES / 32, 512, 0, stream>>>(adj + NN, BTw, out,
                                                          out);
  }
}